// Round 5
// baseline (252.972 us; speedup 1.0000x reference)
//
#include <hip/hip_runtime.h>
#include <stdint.h>

// Q4_0 dequant-GEMM: y[t,o] = sum_k x[t,k] * s[o,k/32]*(q[o,k]-8) + bias[o]
// M=16 tokens, K=4096, N=11008. HBM-bound: 172 MiB int32 qweight stream,
// floor ~29 us at 6.3 TB/s.
//
// R5 (vs R4): alias the cross-wave reduction buffer onto the staging buffer
// (stage data is dead after the MFMA loop; one extra lgkm-only barrier makes
// the reuse safe). LDS 36.25 KB -> exactly 32 KB => 5 blocks/CU instead of 4
// (20 waves/CU, +25% in-flight global_load_lds bytes, +25% cross-block
// overlap of the per-block vmcnt(0) barrier drain). __launch_bounds__(256,5)
// to hold VGPRs under the 5-waves/EU budget.
//
// Structure (unchanged from R4): K-split x8 -> 5504 blocks; per block 4 waves
// x 4 quant-blocks; qweight staged via global_load_lds width=16 (no VGPR
// landing, whole 8 KB/wave parked in the vmcnt queue up front); x (L2-hot)
// prefetched to registers and bf16-packed in-regs; one MFMA
// (f32_16x16x32_bf16) per quant-block; LDS combine + relaxed agent atomicAdd;
// d_out zeroed by a memset graph node.

typedef __attribute__((ext_vector_type(8))) short bf16x8;  // 8 bf16 (4 VGPRs)
typedef __attribute__((ext_vector_type(4))) float f32x4;

#define OUT_F 11008
#define IN_F  4096
#define NB    128      // quant blocks along K
#define KSPLIT 8
#define QB_BLK (NB / KSPLIT)   // 16 quant-blocks per block
#define QB_WV  (QB_BLK / 4)    // 4 quant-blocks (= MFMAs) per wave

__global__ __launch_bounds__(256, 5)
void qgemm_kernel(const float* __restrict__ x,
                  const int* __restrict__ qw,
                  const float* __restrict__ scales,
                  const float* __restrict__ bias,
                  float* __restrict__ out) {
  // 32 KB shared, dual-purpose:
  //  phase 1: stage[wave][s][128] uint4 - staged qweight (2 KB per quant-blk)
  //  phase 2: red[wave][256] float      - cross-wave partial sums (4 KB)
  __shared__ __align__(16) char smem[32768];
  uint4* stage = (uint4*)smem;
  float* red   = (float*)smem;

  const int bid  = blockIdx.x;
  const int kq   = bid & (KSPLIT - 1);
  const int ob   = (bid >> 3) << 4;        // 16 output features per tile
  const int tid  = threadIdx.x;
  const int wave = tid >> 6;
  const int lane = tid & 63;
  const int col  = lane & 15;              // output row (B) / token (A)
  const int kr   = lane >> 4;              // k sub-chunk 0..3

  const int kb0 = kq * QB_BLK + wave * QB_WV;  // first quant-block index

  // Per-lane global source: row (ob+col), quant-block kb0+s, 32 B chunk kr.
  const char* qrow = (const char*)(qw + (size_t)(ob + col) * IN_F)
                   + (size_t)kb0 * 128 + kr * 32;

  // Issue the whole q-stage: 8 x global_load_lds_dwordx4, no VGPR landing.
  // Each instruction pair fetches 16 full 128 B lines (16 rows), each line
  // touched exactly once device-wide. LDS dest = wave-uniform base + lane*16.
#pragma unroll
  for (int s = 0; s < QB_WV; ++s) {
    uint4* dst = stage + (size_t)(wave * QB_WV + s) * 128;
    __builtin_amdgcn_global_load_lds(
        (const __attribute__((address_space(1))) void*)(qrow + s * 128),
        (__attribute__((address_space(3))) void*)dst, 16, 0, 0);
    __builtin_amdgcn_global_load_lds(
        (const __attribute__((address_space(1))) void*)(qrow + s * 128 + 16),
        (__attribute__((address_space(3))) void*)(dst + 64), 16, 0, 0);
  }

  // x prefetch (L2-hot) + per-lane scales; latency overlaps the stage drain.
  const float* xb = x + col * IN_F + kb0 * 32 + kr * 8;
  f32x4 xv[QB_WV][2];
#pragma unroll
  for (int s = 0; s < QB_WV; ++s) {
    xv[s][0] = *(const f32x4*)(xb + s * 32);
    xv[s][1] = *(const f32x4*)(xb + s * 32 + 4);
  }
  f32x4 sv = *(const f32x4*)(scales + (ob + col) * NB + kb0);

  __syncthreads();  // vmcnt(0) drain: staging + x + scales all complete

  f32x4 acc = {0.f, 0.f, 0.f, 0.f};
#pragma unroll
  for (int s = 0; s < QB_WV; ++s) {
    // readback: this lane's 32 B of quants (2 x ds_read_b128, conflict-free)
    const uint4* slot = stage + (size_t)(wave * QB_WV + s) * 128;
    uint4 q0 = slot[lane];
    uint4 q1 = slot[64 + lane];
    float sc  = sv[s];
    float m8s = -8.f * sc;
    union { uint32_t u[4]; bf16x8 v; } A, B;
    // pack x -> bf16 (round-half-up) via v_perm
    uint32_t a0 = __float_as_uint(xv[s][0].x) + 0x8000u;
    uint32_t a1 = __float_as_uint(xv[s][0].y) + 0x8000u;
    uint32_t a2 = __float_as_uint(xv[s][0].z) + 0x8000u;
    uint32_t a3 = __float_as_uint(xv[s][0].w) + 0x8000u;
    uint32_t a4 = __float_as_uint(xv[s][1].x) + 0x8000u;
    uint32_t a5 = __float_as_uint(xv[s][1].y) + 0x8000u;
    uint32_t a6 = __float_as_uint(xv[s][1].z) + 0x8000u;
    uint32_t a7 = __float_as_uint(xv[s][1].w) + 0x8000u;
    A.u[0] = __builtin_amdgcn_perm(a1, a0, 0x07060302u);
    A.u[1] = __builtin_amdgcn_perm(a3, a2, 0x07060302u);
    A.u[2] = __builtin_amdgcn_perm(a5, a4, 0x07060302u);
    A.u[3] = __builtin_amdgcn_perm(a7, a6, 0x07060302u);
    // dequant: w = s*q - 8s (exact in fp32), truncate-pack to bf16
    uint32_t w0 = __float_as_uint(fmaf((float)(int)q0.x, sc, m8s));
    uint32_t w1 = __float_as_uint(fmaf((float)(int)q0.y, sc, m8s));
    uint32_t w2 = __float_as_uint(fmaf((float)(int)q0.z, sc, m8s));
    uint32_t w3 = __float_as_uint(fmaf((float)(int)q0.w, sc, m8s));
    uint32_t w4 = __float_as_uint(fmaf((float)(int)q1.x, sc, m8s));
    uint32_t w5 = __float_as_uint(fmaf((float)(int)q1.y, sc, m8s));
    uint32_t w6 = __float_as_uint(fmaf((float)(int)q1.z, sc, m8s));
    uint32_t w7 = __float_as_uint(fmaf((float)(int)q1.w, sc, m8s));
    B.u[0] = __builtin_amdgcn_perm(w1, w0, 0x07060302u);
    B.u[1] = __builtin_amdgcn_perm(w3, w2, 0x07060302u);
    B.u[2] = __builtin_amdgcn_perm(w5, w4, 0x07060302u);
    B.u[3] = __builtin_amdgcn_perm(w7, w6, 0x07060302u);
    acc = __builtin_amdgcn_mfma_f32_16x16x32_bf16(A.v, B.v, acc, 0, 0, 0);
  }

  // Phase switch: all waves done reading stage before anyone overwrites it.
  __syncthreads();

  // Cross-wave combine. C/D layout: lane holds D[row=kr*4+r][col].
#pragma unroll
  for (int r = 0; r < 4; ++r)
    red[wave * 256 + (kr * 4 + r) * 16 + col] = acc[r];
  __syncthreads();

  float v = red[tid] + red[256 + tid] + red[512 + tid] + red[768 + tid];
  int t = tid >> 4;
  int o = ob + (tid & 15);
  if (kq == 0) v += bias[o];
  __hip_atomic_fetch_add(out + (size_t)t * OUT_F + o, v, __ATOMIC_RELAXED,
                         __HIP_MEMORY_SCOPE_AGENT);
}

// ---------------------------------------------------------------------------
extern "C" void kernel_launch(void* const* d_in, const int* in_sizes, int n_in,
                              void* d_out, int out_size, void* d_ws, size_t ws_size,
                              hipStream_t stream) {
  const float* x      = (const float*)d_in[0];
  const int*   qw     = (const int*)d_in[1];
  const float* scales = (const float*)d_in[2];
  const float* bias   = (const float*)d_in[3];
  float* out = (float*)d_out;

  // zero-init for the atomic K-split accumulation (graph-capturable node)
  hipMemsetAsync(out, 0, (size_t)out_size * sizeof(float), stream);
  // 688 output tiles x 8 K-splits
  qgemm_kernel<<<688 * KSPLIT, 256, 0, stream>>>(x, qw, scales, bias, out);
}